// Round 3
// baseline (725.309 us; speedup 1.0000x reference)
//
#include <hip/hip_runtime.h>
#include <cstdint>
#include <cstddef>

#define DFEAT 512
#define BM 128
#define BN 128
#define BK 32

#define SLABW 32                 // features per slab (64 B per row-slab = 1 cache line)
#define NSLAB (DFEAT / SLABW)    // 16
#define RPW 8                    // rows per wave (8 lanes per row)
#define RPB 32                   // rows per block (4 waves)

typedef __attribute__((ext_vector_type(8))) short bf16x8;
typedef __attribute__((ext_vector_type(4))) float f32x4;

#define GLOBAL_AS __attribute__((address_space(1)))
#define LDS_AS __attribute__((address_space(3)))

// float -> bf16 round-to-nearest-even (finite inputs)
__device__ __forceinline__ unsigned short f2bf(float f) {
  unsigned u = __float_as_uint(f);
  u = u + 0x7fffu + ((u >> 16) & 1u);
  return (unsigned short)(u >> 16);
}

__device__ __forceinline__ float bf2f_lo(unsigned u) { return __uint_as_float(u << 16); }
__device__ __forceinline__ float bf2f_hi(unsigned u) { return __uint_as_float(u & 0xffff0000u); }

__device__ __forceinline__ void gl_lds16(const void* g, void* l) {
  __builtin_amdgcn_global_load_lds((const GLOBAL_AS unsigned int*)g,
                                   (LDS_AS unsigned int*)l, 16, 0, 0);
}

__global__ void k_init(int* __restrict__ deg, int* __restrict__ fill, int N) {
  int i = blockIdx.x * blockDim.x + threadIdx.x;
  if (i < N) { deg[i] = 1; fill[i] = 0; }  // deg starts at 1 for the self-loop
}

__global__ void k_count(const int* __restrict__ dst, int* __restrict__ deg, int E) {
  int i = blockIdx.x * blockDim.x + threadIdx.x;
  if (i < E) atomicAdd(&deg[dst[i]], 1);
}

// single-block exclusive scan of deg -> rowStart[0..N]
__global__ void k_scan(const int* __restrict__ deg, int* __restrict__ rowStart, int N) {
  const int t = threadIdx.x;
  const int C = (N + 1023) / 1024;
  int lo = t * C;
  int hi = lo + C; if (hi > N) hi = N; if (lo > N) lo = N;
  int sum = 0;
  for (int i = lo; i < hi; ++i) sum += deg[i];
  __shared__ int sm[1024];
  sm[t] = sum;
  __syncthreads();
  for (int d = 1; d < 1024; d <<= 1) {
    int v = (t >= d) ? sm[t - d] : 0;
    __syncthreads();
    sm[t] += v;
    __syncthreads();
  }
  int off = sm[t] - sum;  // exclusive prefix for this chunk
  for (int i = lo; i < hi; ++i) { rowStart[i] = off; off += deg[i]; }
  if (t == 1023) rowStart[N] = sm[1023];
}

// cw[pos] = { src, rsqrt(deg[src]) } — dinv computed inline (k_dinv eliminated)
__global__ void k_fill(const int* __restrict__ src, const int* __restrict__ dst,
                       const int* __restrict__ rowStart, int* __restrict__ fill,
                       int2* __restrict__ cw, const int* __restrict__ deg, int E, int N) {
  int i = blockIdx.x * blockDim.x + threadIdx.x;
  if (i >= E + N) return;
  int d, s;
  if (i < E) { d = dst[i]; s = src[i]; }
  else       { d = i - E; s = d; }        // self-loop
  int pos = rowStart[d] + atomicAdd(&fill[d], 1);
  int2 q; q.x = s; q.y = __float_as_int(rsqrtf((float)deg[s]));
  cw[pos] = q;
}

// fused Wt transpose-cast + Xb cast (one launch instead of two)
// blocks [0,1024): Wt[n][k] = bf16(W[k][n]);  blocks [1024,...): Xb = bf16(X)
__global__ void k_wtxb(const float* __restrict__ W, unsigned short* __restrict__ Wt,
                       const float* __restrict__ X, unsigned short* __restrict__ Xb,
                       int total8) {
  if (blockIdx.x < 1024) {
    int i = blockIdx.x * 256 + threadIdx.x;   // i = k*512 + n, coalesced read
    int k = i >> 9, n = i & 511;
    Wt[(size_t)n * DFEAT + k] = f2bf(W[i]);
    return;
  }
  int i = (blockIdx.x - 1024) * 256 + threadIdx.x;
  if (i >= total8) return;
  const float4 a = *reinterpret_cast<const float4*>(X + (size_t)i * 8);
  const float4 c = *reinterpret_cast<const float4*>(X + (size_t)i * 8 + 4);
  uint4 o;
  o.x = (unsigned)f2bf(a.x) | ((unsigned)f2bf(a.y) << 16);
  o.y = (unsigned)f2bf(a.z) | ((unsigned)f2bf(a.w) << 16);
  o.z = (unsigned)f2bf(c.x) | ((unsigned)f2bf(c.y) << 16);
  o.w = (unsigned)f2bf(c.z) | ((unsigned)f2bf(c.w) << 16);
  *reinterpret_cast<uint4*>(Xb + (size_t)i * 8) = o;
}

// Feature-slab-partitioned aggregation.
// Slab s = features [s*32, s*32+32): Xb slab = 50000 x 64B = 3.2 MB -> fits one
// XCD's 4 MB L2. Slab pinned to XCD via round-robin blockIdx&7 dispatch; each
// XCD runs slab xcd (pass 0) then xcd+8 (pass 1) over ALL rows -> slab fetched
// from LLC once per XCD, all 850K edge-reads of it are L2 hits.
// Wave layout: 8 rows x 8 lanes; lane handles 4 feats (8B) -> one edge-slab
// read = one 64B line. cw / Y are single-use streams -> nontemporal, so they
// don't evict the resident slab.
__global__ __launch_bounds__(256) void k_aggregate(const unsigned short* __restrict__ Xb,
                                                   const int2* __restrict__ cw,
                                                   const int* __restrict__ rowStart,
                                                   unsigned short* __restrict__ Y,
                                                   int N, int RB) {
  const int xcd = blockIdx.x & 7;
  const int ord = blockIdx.x >> 3;        // [0, 2*RB)
  const int pass = (ord >= RB) ? 1 : 0;
  const int rb = ord - pass * RB;
  const int slab = xcd + 8 * pass;        // [0,16)
  const int wave = threadIdx.x >> 6;
  const int lane = threadIdx.x & 63;
  const int r = lane >> 3;                // row within wave [0,8)
  const int f = lane & 7;                 // feature quad: feats [f*4, f*4+4)
  const int row = rb * RPB + wave * RPW + r;   // < RB*32 = Mpad always

  int s = 0, deg = 0;
  if (row < N) { s = rowStart[row]; deg = rowStart[row + 1] - s; }  // deg >= 1 (self-loop)

  // wave-uniform trip count: max deg across the 8 row-groups
  int md = deg;
  { int t_ = __shfl_xor(md, 8);  md = md > t_ ? md : t_; }
  { int t_ = __shfl_xor(md, 16); md = md > t_ ? md : t_; }
  { int t_ = __shfl_xor(md, 32); md = md > t_ ? md : t_; }

  const unsigned short* xs = Xb + (size_t)slab * SLABW + (size_t)f * 4;
  float a0 = 0.f, a1 = 0.f, a2 = 0.f, a3 = 0.f;

  for (int t = 0; t < md; t += 4) {
    unsigned long long q[4];
#pragma unroll
    for (int i = 0; i < 4; ++i) {
      int tt = t + i;
      int pi = (tt < deg) ? s + tt : s;   // clamped lanes re-read edge s (cache hit)
      q[i] = __builtin_nontemporal_load(
          reinterpret_cast<const unsigned long long*>(cw + pi));
    }
    uint2 v[4];
#pragma unroll
    for (int i = 0; i < 4; ++i) {
      const int sx = (int)(unsigned)q[i];
      v[i] = *reinterpret_cast<const uint2*>(xs + (size_t)sx * DFEAT);
    }
#pragma unroll
    for (int i = 0; i < 4; ++i) {
      const float w = (t + i < deg) ? __uint_as_float((unsigned)(q[i] >> 32)) : 0.f;
      a0 = fmaf(w, bf2f_lo(v[i].x), a0);
      a1 = fmaf(w, bf2f_hi(v[i].x), a1);
      a2 = fmaf(w, bf2f_lo(v[i].y), a2);
      a3 = fmaf(w, bf2f_hi(v[i].y), a3);
    }
  }
  if (deg > 0) {
    const float sc = rsqrtf((float)deg);
    a0 *= sc; a1 *= sc; a2 *= sc; a3 *= sc;
  }
  unsigned long long o = (unsigned long long)((unsigned)f2bf(a0) | ((unsigned)f2bf(a1) << 16))
                       | ((unsigned long long)((unsigned)f2bf(a2) | ((unsigned)f2bf(a3) << 16)) << 32);
  __builtin_nontemporal_store(o,
      reinterpret_cast<unsigned long long*>(Y + (size_t)row * DFEAT + slab * SLABW + f * 4));
}

// out[M x 512] = LeakyReLU( Y(bf16) @ W + b ). 128x128 tile, BK=32,
// global_load_lds width-16 staging, 4 waves x (64x64 via 4x4 mfma 16x16x32).
// 1D grid, n-fastest + bijective chunked XCD swizzle (m204 form: nwg%8 != 0).
__global__ __launch_bounds__(256) void k_gemm(const unsigned short* __restrict__ Y,
                                              const unsigned short* __restrict__ Wt,
                                              const float* __restrict__ bias,
                                              float* __restrict__ out, int M) {
  __shared__ unsigned short As[BM * BK];  // 8 KB
  __shared__ unsigned short Bs[BN * BK];  // 8 KB
  const int tid = threadIdx.x;
  const int lane = tid & 63;
  const int wave = tid >> 6;
  const int l16 = lane & 15;
  const int quad = lane >> 4;
  const int wm = (wave >> 1) * 64;
  const int wn = (wave & 1) * 64;

  // bijective chunked XCD swizzle (nwg = Mtiles*4 = 1564, q=195, r=4)
  const int nwg = gridDim.x;
  const int q8 = nwg >> 3, r8 = nwg & 7;
  const int xcd = blockIdx.x & 7, loc = blockIdx.x >> 3;
  const int wg = (xcd < r8 ? xcd * (q8 + 1) : r8 * (q8 + 1) + (xcd - r8) * q8) + loc;
  const int m0 = (wg >> 2) * BM;   // n fastest -> A-panel reuse across 4 consecutive wg
  const int n0 = (wg & 3) * BN;

  f32x4 acc[4][4];
#pragma unroll
  for (int mi = 0; mi < 4; ++mi)
#pragma unroll
    for (int ni = 0; ni < 4; ++ni) { f32x4 z = {0.f, 0.f, 0.f, 0.f}; acc[mi][ni] = z; }

  // staging: LDS slot ci (16B units) holds global chunk (row=ci>>2, kq=((ci&3)-(row>>1))&3)
  const int ci0 = wave * 64 + lane;
  const int ci1 = 256 + ci0;
  const int ra0 = ci0 >> 2, ka0 = (((ci0 & 3) - (ra0 >> 1)) & 3) * 8;
  const int ra1 = ci1 >> 2, ka1 = (((ci1 & 3) - (ra1 >> 1)) & 3) * 8;

  const unsigned short* Ag0 = Y + (size_t)(m0 + ra0) * DFEAT + ka0;
  const unsigned short* Ag1 = Y + (size_t)(m0 + ra1) * DFEAT + ka1;
  const unsigned short* Bg0 = Wt + (size_t)(n0 + ra0) * DFEAT + ka0;
  const unsigned short* Bg1 = Wt + (size_t)(n0 + ra1) * DFEAT + ka1;
  unsigned short* La0 = As + ci0 * 8;
  unsigned short* La1 = As + ci1 * 8;
  unsigned short* Lb0 = Bs + ci0 * 8;
  unsigned short* Lb1 = Bs + ci1 * 8;

  // read side: fragment (row, kq=quad) lives at slot row*4 + ((quad + (row>>1)) & 3)
  const int rotA = (quad + ((wm + l16) >> 1)) & 3;   // same for all mi (16*mi/2 % 4 == 0)
  const int rotB = (quad + ((wn + l16) >> 1)) & 3;
  const unsigned short* AsRd = As + (wm + l16) * BK + rotA * 8;
  const unsigned short* BsRd = Bs + (wn + l16) * BK + rotB * 8;

  for (int kk = 0; kk < DFEAT; kk += BK) {
    gl_lds16(Ag0 + kk, La0);
    gl_lds16(Ag1 + kk, La1);
    gl_lds16(Bg0 + kk, Lb0);
    gl_lds16(Bg1 + kk, Lb1);
    __syncthreads();  // drains vmcnt (global_load_lds) per m97 semantics
    bf16x8 av[4], bv[4];
#pragma unroll
    for (int mi = 0; mi < 4; ++mi)
      av[mi] = *reinterpret_cast<const bf16x8*>(AsRd + mi * 16 * BK);
#pragma unroll
    for (int ni = 0; ni < 4; ++ni)
      bv[ni] = *reinterpret_cast<const bf16x8*>(BsRd + ni * 16 * BK);
#pragma unroll
    for (int mi = 0; mi < 4; ++mi)
#pragma unroll
      for (int ni = 0; ni < 4; ++ni)
        acc[mi][ni] = __builtin_amdgcn_mfma_f32_16x16x32_bf16(av[mi], bv[ni], acc[mi][ni], 0, 0, 0);
    __syncthreads();  // protect LDS before next stage
  }

  float bvals[4];
#pragma unroll
  for (int ni = 0; ni < 4; ++ni) bvals[ni] = bias[n0 + wn + 16 * ni + l16];

  // C/D layout: col = lane&15, row = quad*4 + r
#pragma unroll
  for (int mi = 0; mi < 4; ++mi) {
#pragma unroll
    for (int r = 0; r < 4; ++r) {
      int row = m0 + wm + 16 * mi + quad * 4 + r;
      if (row < M) {
#pragma unroll
        for (int ni = 0; ni < 4; ++ni) {
          float v = acc[mi][ni][r] + bvals[ni];
          v = (v >= 0.f) ? v : 0.01f * v;
          out[(size_t)row * DFEAT + n0 + wn + 16 * ni + l16] = v;
        }
      }
    }
  }
}

extern "C" void kernel_launch(void* const* d_in, const int* in_sizes, int n_in,
                              void* d_out, int out_size, void* d_ws, size_t ws_size,
                              hipStream_t stream) {
  const float* X = (const float*)d_in[0];
  const float* W = (const float*)d_in[1];
  const float* b = (const float*)d_in[2];
  const int* ei  = (const int*)d_in[3];
  const int D = DFEAT;
  const int N = in_sizes[0] / D;   // 50000
  const int E = in_sizes[3] / 2;   // 800000
  const int* src = ei;
  const int* dst = ei + E;
  float* out = (float*)d_out;

  // carve workspace (256B-aligned slices)
  uintptr_t p = (uintptr_t)d_ws;
  auto carve = [&](size_t bytes) -> void* {
    uintptr_t r = p;
    p += (bytes + 255) & ~(size_t)255;
    return (void*)r;
  };
  int*   deg      = (int*)carve(sizeof(int) * (size_t)N);
  int*   fill     = (int*)carve(sizeof(int) * (size_t)N);
  int*   rowStart = (int*)carve(sizeof(int) * (size_t)(N + 1));
  int2*  cw       = (int2*)carve(sizeof(int2) * (size_t)(E + N));
  unsigned short* Wt = (unsigned short*)carve(sizeof(unsigned short) * (size_t)D * D);
  const int Mtiles = (N + BM - 1) / BM;     // 391
  const int Mpad = Mtiles * BM;             // 50048
  unsigned short* Y  = (unsigned short*)carve(sizeof(unsigned short) * (size_t)Mpad * D);

  // Xb (bf16 X) lives in d_out: 51.2 MB needed, 102.4 MB available; dead before k_gemm writes.
  unsigned short* Xb = (unsigned short*)d_out;

  const int total8 = N * D / 8;
  const int RB = Mpad / RPB;                // 1564 row-blocks of 32 rows

  hipLaunchKernelGGL(k_init,  dim3((N + 255) / 256), dim3(256), 0, stream, deg, fill, N);
  hipLaunchKernelGGL(k_count, dim3((E + 255) / 256), dim3(256), 0, stream, dst, deg, E);
  hipLaunchKernelGGL(k_scan,  dim3(1), dim3(1024), 0, stream, deg, rowStart, N);
  hipLaunchKernelGGL(k_fill,  dim3((E + N + 255) / 256), dim3(256), 0, stream,
                     src, dst, rowStart, fill, cw, deg, E, N);
  hipLaunchKernelGGL(k_wtxb,  dim3(1024 + (total8 + 255) / 256), dim3(256), 0, stream,
                     W, Wt, X, Xb, total8);
  hipLaunchKernelGGL(k_aggregate, dim3(16 * RB), dim3(256), 0, stream,
                     Xb, cw, rowStart, Y, N, RB);
  hipLaunchKernelGGL(k_gemm,  dim3(Mtiles * 4), dim3(256), 0, stream, Y, Wt, b, out, N);
}

// Round 4
// 454.700 us; speedup vs baseline: 1.5951x; 1.5951x over previous
//
#include <hip/hip_runtime.h>
#include <cstdint>
#include <cstddef>

#define DFEAT 512
#define BM 128
#define BN 128
#define BK 32

typedef __attribute__((ext_vector_type(8))) short bf16x8;
typedef __attribute__((ext_vector_type(4))) float f32x4;

#define GLOBAL_AS __attribute__((address_space(1)))
#define LDS_AS __attribute__((address_space(3)))

// float -> bf16 round-to-nearest-even (finite inputs)
__device__ __forceinline__ unsigned short f2bf(float f) {
  unsigned u = __float_as_uint(f);
  u = u + 0x7fffu + ((u >> 16) & 1u);
  return (unsigned short)(u >> 16);
}

__device__ __forceinline__ float bf2f_lo(unsigned u) { return __uint_as_float(u << 16); }
__device__ __forceinline__ float bf2f_hi(unsigned u) { return __uint_as_float(u & 0xffff0000u); }

__device__ __forceinline__ void gl_lds16(const void* g, void* l) {
  __builtin_amdgcn_global_load_lds((const GLOBAL_AS unsigned int*)g,
                                   (LDS_AS unsigned int*)l, 16, 0, 0);
}

__global__ void k_init(int* __restrict__ deg, int N) {
  int i = blockIdx.x * blockDim.x + threadIdx.x;
  if (i < N) deg[i] = 1;  // deg starts at 1 for the self-loop
}

__global__ void k_count(const int* __restrict__ dst, int* __restrict__ deg, int E) {
  int i = blockIdx.x * blockDim.x + threadIdx.x;
  if (i < E) atomicAdd(&deg[dst[i]], 1);
}

// single-block exclusive scan of deg -> rowStart[0..N] and fillPos[0..N)
// (fillPos is the atomically-bumped cursor copy used by k_fill).
// LDS-tiled: 4096 elems/tile via int4 loads (coalesced), Hillis-Steele in LDS.
__global__ __launch_bounds__(1024) void k_scan(const int* __restrict__ deg,
                                               int* __restrict__ rowStart,
                                               int* __restrict__ fillPos, int N) {
  const int t = threadIdx.x;
  __shared__ int sm[1024];
  __shared__ int carrySm;
  if (t == 0) carrySm = 0;
  for (int base = 0; base < N; base += 4096) {
    const int idx = base + t * 4;
    int4 v = make_int4(0, 0, 0, 0);
    if (idx + 3 < N) {
      v = *reinterpret_cast<const int4*>(deg + idx);
    } else if (idx < N) {
      v.x = deg[idx];
      if (idx + 1 < N) v.y = deg[idx + 1];
      if (idx + 2 < N) v.z = deg[idx + 2];
    }
    const int s4 = v.x + v.y + v.z + v.w;
    __syncthreads();                 // prev tile fully done with sm / carrySm
    sm[t] = s4;
    __syncthreads();
    for (int d = 1; d < 1024; d <<= 1) {
      const int o = (t >= d) ? sm[t - d] : 0;
      __syncthreads();
      sm[t] += o;
      __syncthreads();
    }
    const int incl = sm[t];
    const int carry = carrySm;
    __syncthreads();                 // everyone read carrySm before the update
    if (t == 1023) carrySm = carry + incl;
    const int e0 = carry + incl - s4;
    if (idx + 3 < N) {
      int4 o4 = make_int4(e0, e0 + v.x, e0 + v.x + v.y, e0 + v.x + v.y + v.z);
      *reinterpret_cast<int4*>(rowStart + idx) = o4;
      *reinterpret_cast<int4*>(fillPos + idx) = o4;
    } else if (idx < N) {
      rowStart[idx] = e0; fillPos[idx] = e0;
      if (idx + 1 < N) { rowStart[idx + 1] = e0 + v.x; fillPos[idx + 1] = e0 + v.x; }
      if (idx + 2 < N) { rowStart[idx + 2] = e0 + v.x + v.y; fillPos[idx + 2] = e0 + v.x + v.y; }
    }
  }
  __syncthreads();
  if (t == 0) rowStart[N] = carrySm;
}

// cw[pos] = { src, rsqrt(deg[src]) }; pos straight from the fillPos cursor
// (single dependent atomic; the old rowStart[d] random load is gone).
__global__ void k_fill(const int* __restrict__ src, const int* __restrict__ dst,
                       int* __restrict__ fillPos, int2* __restrict__ cw,
                       const int* __restrict__ deg, int E, int N) {
  int i = blockIdx.x * blockDim.x + threadIdx.x;
  if (i >= E + N) return;
  int d, s;
  if (i < E) { d = dst[i]; s = src[i]; }
  else       { d = i - E; s = d; }        // self-loop
  int pos = atomicAdd(&fillPos[d], 1);
  int2 q; q.x = s; q.y = __float_as_int(rsqrtf((float)deg[s]));
  cw[pos] = q;
}

// fused Wt transpose-cast + Xb cast (one launch instead of two)
// blocks [0,1024): Wt[n][k] = bf16(W[k][n]);  blocks [1024,...): Xb = bf16(X)
__global__ void k_wtxb(const float* __restrict__ W, unsigned short* __restrict__ Wt,
                       const float* __restrict__ X, unsigned short* __restrict__ Xb,
                       int total8) {
  if (blockIdx.x < 1024) {
    int i = blockIdx.x * 256 + threadIdx.x;   // i = k*512 + n, coalesced read
    int k = i >> 9, n = i & 511;
    Wt[(size_t)n * DFEAT + k] = f2bf(W[i]);
    return;
  }
  int i = (blockIdx.x - 1024) * 256 + threadIdx.x;
  if (i >= total8) return;
  const float4 a = *reinterpret_cast<const float4*>(X + (size_t)i * 8);
  const float4 c = *reinterpret_cast<const float4*>(X + (size_t)i * 8 + 4);
  uint4 o;
  o.x = (unsigned)f2bf(a.x) | ((unsigned)f2bf(a.y) << 16);
  o.y = (unsigned)f2bf(a.z) | ((unsigned)f2bf(a.w) << 16);
  o.z = (unsigned)f2bf(c.x) | ((unsigned)f2bf(c.y) << 16);
  o.w = (unsigned)f2bf(c.z) | ((unsigned)f2bf(c.w) << 16);
  *reinterpret_cast<uint4*>(Xb + (size_t)i * 8) = o;
}

// 8-deep gather batch: 8 independent cw loads then 8 independent 1KB row
// gathers in flight per wave. TAIL variant clamps the index to e-1 and zeroes
// the weight — duplicate clamped loads are same-address (L1-hit).
template <bool TAIL>
__device__ __forceinline__ void agg8(const unsigned short* __restrict__ Xb,
                                     const int2* __restrict__ cw,
                                     int p, int e, int lane, float* acc) {
  int2 q[8];
#pragma unroll
  for (int i = 0; i < 8; ++i) {
    int pi = p + i;
    if (TAIL) pi = (pi < e) ? pi : (e - 1);
    q[i] = cw[pi];
  }
  uint4 v[8];
#pragma unroll
  for (int i = 0; i < 8; ++i)
    v[i] = *reinterpret_cast<const uint4*>(Xb + (size_t)q[i].x * DFEAT + lane * 8);
#pragma unroll
  for (int i = 0; i < 8; ++i) {
    float w = __int_as_float(q[i].y);
    if (TAIL) w = (p + i < e) ? w : 0.0f;
    acc[0] = fmaf(w, bf2f_lo(v[i].x), acc[0]); acc[1] = fmaf(w, bf2f_hi(v[i].x), acc[1]);
    acc[2] = fmaf(w, bf2f_lo(v[i].y), acc[2]); acc[3] = fmaf(w, bf2f_hi(v[i].y), acc[3]);
    acc[4] = fmaf(w, bf2f_lo(v[i].z), acc[4]); acc[5] = fmaf(w, bf2f_hi(v[i].z), acc[5]);
    acc[6] = fmaf(w, bf2f_lo(v[i].w), acc[6]); acc[7] = fmaf(w, bf2f_hi(v[i].w), acc[7]);
  }
}

// One wave per dst row; lane handles features [lane*8, lane*8+8).
// Launched twice (half the rows each) so the harness's top-5 duration window
// drops to ~60 µs and exposes the mid-tier kernels for profiling.
__global__ __launch_bounds__(256) void k_aggregate(const unsigned short* __restrict__ Xb,
                                                   const int2* __restrict__ cw,
                                                   const int* __restrict__ rowStart,
                                                   const int* __restrict__ deg,
                                                   unsigned short* __restrict__ Y,
                                                   int N, int rowOff) {
  const int row = rowOff + blockIdx.x * 4 + (threadIdx.x >> 6);
  const int lane = threadIdx.x & 63;
  float acc[8] = {0.f, 0.f, 0.f, 0.f, 0.f, 0.f, 0.f, 0.f};
  if (row < N) {
    const int s = rowStart[row], e = rowStart[row + 1];  // e > s always (self-loop)
    int p = s;
    for (; p + 8 <= e; p += 8) agg8<false>(Xb, cw, p, e, lane, acc);
    if (p < e) agg8<true>(Xb, cw, p, e, lane, acc);
    const float sc = rsqrtf((float)deg[row]);
#pragma unroll
    for (int j = 0; j < 8; ++j) acc[j] *= sc;
  }
  uint4 o;
  o.x = (unsigned)f2bf(acc[0]) | ((unsigned)f2bf(acc[1]) << 16);
  o.y = (unsigned)f2bf(acc[2]) | ((unsigned)f2bf(acc[3]) << 16);
  o.z = (unsigned)f2bf(acc[4]) | ((unsigned)f2bf(acc[5]) << 16);
  o.w = (unsigned)f2bf(acc[6]) | ((unsigned)f2bf(acc[7]) << 16);
  *reinterpret_cast<uint4*>(Y + (size_t)row * DFEAT + lane * 8) = o;
}

// out[M x 512] = LeakyReLU( Y(bf16) @ W + b ). 128x128 tile, BK=32,
// global_load_lds width-16 staging, 4 waves x (64x64 via 4x4 mfma 16x16x32).
// 1D grid, n-fastest + bijective chunked XCD swizzle (m204 form: nwg%8 != 0).
__global__ __launch_bounds__(256) void k_gemm(const unsigned short* __restrict__ Y,
                                              const unsigned short* __restrict__ Wt,
                                              const float* __restrict__ bias,
                                              float* __restrict__ out, int M) {
  __shared__ unsigned short As[BM * BK];  // 8 KB
  __shared__ unsigned short Bs[BN * BK];  // 8 KB
  const int tid = threadIdx.x;
  const int lane = tid & 63;
  const int wave = tid >> 6;
  const int l16 = lane & 15;
  const int quad = lane >> 4;
  const int wm = (wave >> 1) * 64;
  const int wn = (wave & 1) * 64;

  // bijective chunked XCD swizzle (nwg = Mtiles*4 = 1564, q=195, r=4)
  const int nwg = gridDim.x;
  const int q8 = nwg >> 3, r8 = nwg & 7;
  const int xcd = blockIdx.x & 7, loc = blockIdx.x >> 3;
  const int wg = (xcd < r8 ? xcd * (q8 + 1) : r8 * (q8 + 1) + (xcd - r8) * q8) + loc;
  const int m0 = (wg >> 2) * BM;   // n fastest -> A-panel reuse across 4 consecutive wg
  const int n0 = (wg & 3) * BN;

  f32x4 acc[4][4];
#pragma unroll
  for (int mi = 0; mi < 4; ++mi)
#pragma unroll
    for (int ni = 0; ni < 4; ++ni) { f32x4 z = {0.f, 0.f, 0.f, 0.f}; acc[mi][ni] = z; }

  // staging: LDS slot ci (16B units) holds global chunk (row=ci>>2, kq=((ci&3)-(row>>1))&3)
  const int ci0 = wave * 64 + lane;
  const int ci1 = 256 + ci0;
  const int ra0 = ci0 >> 2, ka0 = (((ci0 & 3) - (ra0 >> 1)) & 3) * 8;
  const int ra1 = ci1 >> 2, ka1 = (((ci1 & 3) - (ra1 >> 1)) & 3) * 8;

  const unsigned short* Ag0 = Y + (size_t)(m0 + ra0) * DFEAT + ka0;
  const unsigned short* Ag1 = Y + (size_t)(m0 + ra1) * DFEAT + ka1;
  const unsigned short* Bg0 = Wt + (size_t)(n0 + ra0) * DFEAT + ka0;
  const unsigned short* Bg1 = Wt + (size_t)(n0 + ra1) * DFEAT + ka1;
  unsigned short* La0 = As + ci0 * 8;
  unsigned short* La1 = As + ci1 * 8;
  unsigned short* Lb0 = Bs + ci0 * 8;
  unsigned short* Lb1 = Bs + ci1 * 8;

  // read side: fragment (row, kq=quad) lives at slot row*4 + ((quad + (row>>1)) & 3)
  const int rotA = (quad + ((wm + l16) >> 1)) & 3;   // same for all mi (16*mi/2 % 4 == 0)
  const int rotB = (quad + ((wn + l16) >> 1)) & 3;
  const unsigned short* AsRd = As + (wm + l16) * BK + rotA * 8;
  const unsigned short* BsRd = Bs + (wn + l16) * BK + rotB * 8;

  for (int kk = 0; kk < DFEAT; kk += BK) {
    gl_lds16(Ag0 + kk, La0);
    gl_lds16(Ag1 + kk, La1);
    gl_lds16(Bg0 + kk, Lb0);
    gl_lds16(Bg1 + kk, Lb1);
    __syncthreads();  // drains vmcnt (global_load_lds) per m97 semantics
    bf16x8 av[4], bv[4];
#pragma unroll
    for (int mi = 0; mi < 4; ++mi)
      av[mi] = *reinterpret_cast<const bf16x8*>(AsRd + mi * 16 * BK);
#pragma unroll
    for (int ni = 0; ni < 4; ++ni)
      bv[ni] = *reinterpret_cast<const bf16x8*>(BsRd + ni * 16 * BK);
#pragma unroll
    for (int mi = 0; mi < 4; ++mi)
#pragma unroll
      for (int ni = 0; ni < 4; ++ni)
        acc[mi][ni] = __builtin_amdgcn_mfma_f32_16x16x32_bf16(av[mi], bv[ni], acc[mi][ni], 0, 0, 0);
    __syncthreads();  // protect LDS before next stage
  }

  float bvals[4];
#pragma unroll
  for (int ni = 0; ni < 4; ++ni) bvals[ni] = bias[n0 + wn + 16 * ni + l16];

  // C/D layout: col = lane&15, row = quad*4 + r
#pragma unroll
  for (int mi = 0; mi < 4; ++mi) {
#pragma unroll
    for (int r = 0; r < 4; ++r) {
      int row = m0 + wm + 16 * mi + quad * 4 + r;
      if (row < M) {
#pragma unroll
        for (int ni = 0; ni < 4; ++ni) {
          float v = acc[mi][ni][r] + bvals[ni];
          v = (v >= 0.f) ? v : 0.01f * v;
          out[(size_t)row * DFEAT + n0 + wn + 16 * ni + l16] = v;
        }
      }
    }
  }
}

extern "C" void kernel_launch(void* const* d_in, const int* in_sizes, int n_in,
                              void* d_out, int out_size, void* d_ws, size_t ws_size,
                              hipStream_t stream) {
  const float* X = (const float*)d_in[0];
  const float* W = (const float*)d_in[1];
  const float* b = (const float*)d_in[2];
  const int* ei  = (const int*)d_in[3];
  const int D = DFEAT;
  const int N = in_sizes[0] / D;   // 50000
  const int E = in_sizes[3] / 2;   // 800000
  const int* src = ei;
  const int* dst = ei + E;
  float* out = (float*)d_out;

  // carve workspace (256B-aligned slices)
  uintptr_t p = (uintptr_t)d_ws;
  auto carve = [&](size_t bytes) -> void* {
    uintptr_t r = p;
    p += (bytes + 255) & ~(size_t)255;
    return (void*)r;
  };
  int*   deg      = (int*)carve(sizeof(int) * (size_t)N);
  int*   rowStart = (int*)carve(sizeof(int) * (size_t)(N + 1));
  int*   fillPos  = (int*)carve(sizeof(int) * (size_t)N);
  int2*  cw       = (int2*)carve(sizeof(int2) * (size_t)(E + N));
  unsigned short* Wt = (unsigned short*)carve(sizeof(unsigned short) * (size_t)D * D);
  const int Mtiles = (N + BM - 1) / BM;     // 391
  const int Mpad = Mtiles * BM;             // 50048
  unsigned short* Y  = (unsigned short*)carve(sizeof(unsigned short) * (size_t)Mpad * D);

  // Xb (bf16 X) lives in d_out: 51.2 MB needed, 102.4 MB available; dead before k_gemm writes.
  unsigned short* Xb = (unsigned short*)d_out;

  const int total8 = N * D / 8;
  const int half = (Mpad / 2 + 3) & ~3;     // 25024, multiple of 4 rows/block

  hipLaunchKernelGGL(k_init,  dim3((N + 255) / 256), dim3(256), 0, stream, deg, N);
  hipLaunchKernelGGL(k_count, dim3((E + 255) / 256), dim3(256), 0, stream, dst, deg, E);
  hipLaunchKernelGGL(k_scan,  dim3(1), dim3(1024), 0, stream, deg, rowStart, fillPos, N);
  hipLaunchKernelGGL(k_fill,  dim3((E + N + 255) / 256), dim3(256), 0, stream,
                     src, dst, fillPos, cw, deg, E, N);
  hipLaunchKernelGGL(k_wtxb,  dim3(1024 + (total8 + 255) / 256), dim3(256), 0, stream,
                     W, Wt, X, Xb, total8);
  hipLaunchKernelGGL(k_aggregate, dim3(half / 4), dim3(256), 0, stream,
                     Xb, cw, rowStart, deg, Y, N, 0);
  hipLaunchKernelGGL(k_aggregate, dim3((Mpad - half) / 4), dim3(256), 0, stream,
                     Xb, cw, rowStart, deg, Y, N, half);
  hipLaunchKernelGGL(k_gemm,  dim3(Mtiles * 4), dim3(256), 0, stream, Y, Wt, b, out, N);
}